// Round 6
// baseline (229.910 us; speedup 1.0000x reference)
//
#include <hip/hip_runtime.h>

// B-spline basis (Cox-de Boor), degree 3, 256 knots, 252 basis fns, N=1M.
// Round-6: persistent blocks + DOUBLE-BUFFERED 32-row LDS image.
//  - stream tile t from buf[cur] (ds_read_b128 + global_store_dwordx4, ~3
//    instr / 16B, no selects)  [R5's stream]
//  - band-compute tile t+1 into buf[nxt] DURING the stream (x-load + divide
//    recursion hides under store drain)                     [kills R5's serial bubble]
//  - raw s_barrier + lgkmcnt(0) only; vmcnt NEVER drained in the loop, so
//    stores pipeline across tiles                           [kills R5's vmcnt(0) drain]
// LDS image zeroed once; per tile only the <=2 band chunks per row are
// cleared (previous) and rewritten (new).

constexpr int NUM_KNOTS = 256;
constexpr int NUM_BASIS = 252;       // NUM_KNOTS - DEGREE - 1
constexpr int CHUNKS    = 63;        // float4 chunks per row (1008 B)
constexpr int TROWS     = 32;        // rows per tile
constexpr int TILE_F4   = TROWS * CHUNKS;   // 2016 f4 = 31.5 KB
constexpr int BLOCK     = 256;

typedef float f4 __attribute__((ext_vector_type(4)));

__device__ __forceinline__ void cox_de_boor(float x, const float* sk,
                                            int& clo_out, f4& vlo_out, f4& vhi_out)
{
    float k0 = sk[0], kend = sk[NUM_KNOTS - 1];
    float inv_h = (float)(NUM_KNOTS - 1) / (kend - k0);
    int j0 = (int)floorf((x - k0) * inv_h);
    j0 = min(max(j0, 0), NUM_KNOTS - 2);
    while (j0 > 0 && x < sk[j0]) --j0;
    while (j0 < NUM_KNOTS - 2 && x >= sk[j0 + 1]) ++j0;

    // cb[i] at level k holds B_{j0-k+i, k}; level 0: B_{j0,0} = 1
    float cb[4] = {1.0f, 0.0f, 0.0f, 0.0f};
    #pragma unroll
    for (int k = 1; k <= 3; ++k) {
        #pragma unroll
        for (int i = 3; i >= 0; --i) {           // downward: in-place safe
            if (i > k) continue;
            int j = j0 - k + i;
            float plo = (i >= 1)     ? cb[i - 1] : 0.0f;  // B_{j,  k-1}
            float phi = (i <= k - 1) ? cb[i]     : 0.0f;  // B_{j+1,k-1}
            float val = 0.0f;
            // reference truncation: level-k valid for j in [0, 254-k]
            if (j >= 0 && j <= NUM_KNOTS - 2 - k) {
                float kj  = sk[j];
                float kj1 = sk[j + 1];
                float kjk = sk[j + k];
                float kk1 = sk[j + k + 1];
                val = (x - kj) / (kjk - kj) * plo
                    + (kk1 - x) / (kk1 - kj1) * phi;
            }
            cb[i] = val;
        }
    }

    // Band cols j0-3..j0 -> aligned chunks clo=(j0-3)>>2 and clo+1, split at
    // a=(j0-3)&3 via conditional register shifts (static indices only).
    int s = j0 - 3, a = s & 3, clo = s >> 2;     // -3..-1 -> clo = -1
    float lo0=cb[0], lo1=cb[1], lo2=cb[2], lo3=cb[3];
    float hi0=0.f, hi1=0.f, hi2=0.f, hi3=0.f;
    if (a & 2) { hi3=hi1; hi2=hi0; hi1=lo3; hi0=lo2;
                 lo3=lo1; lo2=lo0; lo1=0.f; lo0=0.f; }
    if (a & 1) { hi3=hi2; hi2=hi1; hi1=hi0; hi0=lo3;
                 lo3=lo2; lo2=lo1; lo1=lo0; lo0=0.f; }
    f4 vlo; vlo.x=lo0; vlo.y=lo1; vlo.z=lo2; vlo.w=lo3;
    f4 vhi; vhi.x=hi0; vhi.y=hi1; vhi.z=hi2; vhi.w=hi3;
    clo_out = clo; vlo_out = vlo; vhi_out = vhi;
}

__device__ __forceinline__ void write_band(f4* img, int lane, int& prev,
                                           bool valid, int clo, f4 vlo, f4 vhi)
{
    f4* rowimg = img + lane * CHUNKS;
    f4 z = (f4)0.0f;
    if (prev > -99) {                            // clear band from 2 tiles ago
        if (prev >= 0)          rowimg[prev]     = z;
        if (prev < CHUNKS - 1)  rowimg[prev + 1] = z;
    }
    if (valid) {
        if (clo >= 0)           rowimg[clo]      = vlo;
        if (clo < CHUNKS - 1)   rowimg[clo + 1]  = vhi;
        prev = clo;
    } else {
        prev = -100;
    }
}

__global__ __launch_bounds__(BLOCK) void bspline_kernel(
    const float* __restrict__ X, const float* __restrict__ knots,
    float* __restrict__ out, int n, int ntiles, int K)
{
    __shared__ float s_knots[NUM_KNOTS];
    __shared__ f4    imgA[TILE_F4];
    __shared__ f4    imgB[TILE_F4];

    const int tid  = threadIdx.x;
    const int t0   = blockIdx.x * K;
    const int tend = min(t0 + K, ntiles);
    if (t0 >= tend) return;                      // block-uniform

    s_knots[tid] = knots[tid];
    for (int i = tid; i < TILE_F4; i += BLOCK) { imgA[i] = (f4)0.0f; imgB[i] = (f4)0.0f; }
    __syncthreads();

    int prevA = -100, prevB = -100;              // per band-lane (tid < 32)

    // prologue: band(t0) -> A
    if (tid < TROWS) {
        int row = t0 * TROWS + tid;
        float x = X[min(row, n - 1)];
        int clo; f4 vlo, vhi;
        cox_de_boor(x, s_knots, clo, vlo, vhi);
        write_band(imgA, tid, prevA, row < n, clo, vlo, vhi);
    }
    asm volatile("s_waitcnt lgkmcnt(0)" ::: "memory");
    __builtin_amdgcn_s_barrier();

    for (int t = t0; t < tend; ++t) {
        const bool curA = ((t - t0) & 1) == 0;
        const f4* cur = curA ? imgA : imgB;      // uniform pointer select

        // ---- stream tile t: LDS -> HBM, stores never drained in-loop ----
        const int tbase = t * TROWS;
        f4* dst = (f4*)out + (size_t)tbase * CHUNKS;
        if (tbase + TROWS <= n) {                // full tile (always, N=1M)
            #pragma unroll
            for (int i = 0; i < 7; ++i)          // 7*256 = 1792
                dst[tid + 256 * i] = cur[tid + 256 * i];
            if (tid < TILE_F4 - 7 * 256)         // remainder: 224 threads
                dst[tid + 7 * 256] = cur[tid + 7 * 256];
        } else {                                 // tail tile
            int lim = (n - tbase) * CHUNKS;
            for (int i = tid; i < lim; i += BLOCK) dst[i] = cur[i];
        }

        // ---- band(t+1) -> other buffer, overlapped with store drain ----
        if (t + 1 < tend && tid < TROWS) {
            int row = (t + 1) * TROWS + tid;
            float x = X[min(row, n - 1)];
            int clo; f4 vlo, vhi;
            cox_de_boor(x, s_knots, clo, vlo, vhi);
            if (curA) write_band(imgB, tid, prevB, row < n, clo, vlo, vhi);
            else      write_band(imgA, tid, prevA, row < n, clo, vlo, vhi);
        }

        // LDS-only fence: ds_reads of cur + ds_writes of nxt done; stores
        // stay in flight (vmcnt back-pressure paces the loop, not drains).
        asm volatile("s_waitcnt lgkmcnt(0)" ::: "memory");
        __builtin_amdgcn_s_barrier();
    }
}

extern "C" void kernel_launch(void* const* d_in, const int* in_sizes, int n_in,
                              void* d_out, int out_size, void* d_ws, size_t ws_size,
                              hipStream_t stream) {
    const float* x     = (const float*)d_in[0];
    const float* knots = (const float*)d_in[1];
    float* out = (float*)d_out;
    int n = in_sizes[0];
    int ntiles = (n + TROWS - 1) / TROWS;        // 32768 for N=1M
    int grid = ntiles < 512 ? ntiles : 512;      // 2 blocks/CU (64 KB LDS each)
    int K = (ntiles + grid - 1) / grid;          // consecutive tiles per block
    bspline_kernel<<<grid, BLOCK, 0, stream>>>(x, knots, out, n, ntiles, K);
}

// Round 7
// 210.186 us; speedup vs baseline: 1.0938x; 1.0938x over previous
//
#include <hip/hip_runtime.h>

// B-spline basis (Cox-de Boor), degree 3, 256 knots, 252 basis fns, N=1M.
// Round-7: ZERO LDS / ZERO barriers in the store loop.
//   phase 1: lane l computes row (rbase+l)'s band -> REGISTERS (clo,vlo,vhi)
//   phase 2: 64 iterations; iter i broadcasts lane i's 9 values via
//            v_readlane (SGPR, no LDS), all 64 lanes emit row rbase+i's 63
//            float4 chunks as ONE coalesced 1008B store. Value = 2 SGPR
//            compares + 8 cndmask. ~22 instr + 1 store per 1008 B.
// R3/R5/R6 all kept LDS on the store critical path (R3: 40B LDS read per
// 16B store ~= the ds_read_b128 ceiling at 6.5TB/s pace). fillBuffer does
// 6.8 TB/s with zero LDS per store; this clones that structure.

constexpr int NUM_KNOTS = 256;
constexpr int NUM_BASIS = 252;       // NUM_KNOTS - DEGREE - 1
constexpr int CHUNKS    = 63;        // float4 chunks per row (1008 B)
constexpr int BLOCK     = 256;       // 4 waves, 64 rows/wave, 256 rows/block

typedef float f4 __attribute__((ext_vector_type(4)));

__device__ __forceinline__ float bcastf(float v, int lane) {
    return __uint_as_float(
        (unsigned)__builtin_amdgcn_readlane(__float_as_uint(v), lane));
}

__global__ __launch_bounds__(BLOCK) void bspline_kernel(
    const float* __restrict__ X, const float* __restrict__ knots,
    float* __restrict__ out, int n)
{
    __shared__ float s_knots[NUM_KNOTS];
    const int tid  = threadIdx.x;
    const int lane = tid & 63;
    const int rbase = blockIdx.x * BLOCK + (tid >> 6 << 6);  // wave's 64 rows

    s_knots[tid] = knots[tid];
    __syncthreads();

    // ---------- phase 1: per-lane Cox-de Boor -> band in registers ----------
    const int myrow = rbase + lane;
    float x    = X[min(myrow, n - 1)];
    float k0   = s_knots[0];
    float kend = s_knots[NUM_KNOTS - 1];
    float inv_h = (float)(NUM_KNOTS - 1) / (kend - k0);

    int j0 = (int)floorf((x - k0) * inv_h);
    j0 = min(max(j0, 0), NUM_KNOTS - 2);
    while (j0 > 0 && x < s_knots[j0]) --j0;
    while (j0 < NUM_KNOTS - 2 && x >= s_knots[j0 + 1]) ++j0;

    // cb[i] at level k holds B_{j0-k+i, k}; level 0: B_{j0,0} = 1
    float cb[4] = {1.0f, 0.0f, 0.0f, 0.0f};
    #pragma unroll
    for (int k = 1; k <= 3; ++k) {
        #pragma unroll
        for (int i = 3; i >= 0; --i) {           // downward: in-place safe
            if (i > k) continue;
            int j = j0 - k + i;
            float plo = (i >= 1)     ? cb[i - 1] : 0.0f;  // B_{j,  k-1}
            float phi = (i <= k - 1) ? cb[i]     : 0.0f;  // B_{j+1,k-1}
            float val = 0.0f;
            // reference truncation: level-k valid for j in [0, 254-k]
            if (j >= 0 && j <= NUM_KNOTS - 2 - k) {
                float kj  = s_knots[j];
                float kj1 = s_knots[j + 1];
                float kjk = s_knots[j + k];
                float kk1 = s_knots[j + k + 1];
                val = (x - kj) / (kjk - kj) * plo
                    + (kk1 - x) / (kk1 - kj1) * phi;
            }
            cb[i] = val;
        }
    }

    // Band cols j0-3..j0 -> aligned chunks clo=(j0-3)>>2 and clo+1, split at
    // a=(j0-3)&3 via conditional register shifts (static indices only).
    int s = j0 - 3, a = s & 3, clo = s >> 2;     // -3..-1 -> clo = -1
    float lo0=cb[0], lo1=cb[1], lo2=cb[2], lo3=cb[3];
    float hi0=0.f, hi1=0.f, hi2=0.f, hi3=0.f;
    if (a & 2) { hi3=hi1; hi2=hi0; hi1=lo3; hi0=lo2;
                 lo3=lo1; lo2=lo0; lo1=0.f; lo0=0.f; }
    if (a & 1) { hi3=hi2; hi2=hi1; hi1=hi0; hi0=lo3;
                 lo3=lo2; lo2=lo1; lo1=lo0; lo0=0.f; }
    // clo == -1 (j0<=2): valid part is vhi at chunk 0 (lane==clo never hits).
    // clo == 62 (j0==254): vhi would be chunk 63 -> dropped by lane<63 guard
    // (those cols are truncated away by the reference anyway).

    // ---------- phase 2: wave-broadcast store stream, no LDS ----------
    float* outp = out + (size_t)rbase * NUM_BASIS;
    const bool full = (rbase + 64 <= n);         // wave-uniform; true @ N=1M
    const bool storer = (lane < CHUNKS);

    #pragma unroll 4
    for (int i = 0; i < 64; ++i) {
        int   sclo = __builtin_amdgcn_readlane(clo, i);
        float sl0 = bcastf(lo0, i), sl1 = bcastf(lo1, i),
              sl2 = bcastf(lo2, i), sl3 = bcastf(lo3, i);
        float sh0 = bcastf(hi0, i), sh1 = bcastf(hi1, i),
              sh2 = bcastf(hi2, i), sh3 = bcastf(hi3, i);
        bool blo = (lane == sclo);
        bool bhi = (lane == sclo + 1);
        f4 v;
        v.x = blo ? sl0 : (bhi ? sh0 : 0.0f);
        v.y = blo ? sl1 : (bhi ? sh1 : 0.0f);
        v.z = blo ? sl2 : (bhi ? sh2 : 0.0f);
        v.w = blo ? sl3 : (bhi ? sh3 : 0.0f);
        if (storer && (full || rbase + i < n)) {
            f4* dst = (f4*)(outp + (size_t)i * NUM_BASIS) + lane;
            *dst = v;                            // 63 lanes: 1008B coalesced
        }
    }
}

extern "C" void kernel_launch(void* const* d_in, const int* in_sizes, int n_in,
                              void* d_out, int out_size, void* d_ws, size_t ws_size,
                              hipStream_t stream) {
    const float* x     = (const float*)d_in[0];
    const float* knots = (const float*)d_in[1];
    float* out = (float*)d_out;
    int n = in_sizes[0];
    int grid = (n + BLOCK - 1) / BLOCK;          // 4096 for N=1M
    bspline_kernel<<<grid, BLOCK, 0, stream>>>(x, knots, out, n);
}